// Round 9
// baseline (275.489 us; speedup 1.0000x reference)
//
#include <hip/hip_runtime.h>

#define BB 4
#define NN 256
#define DD 256
#define HH 256
#define NEGV -1.0e9f

typedef _Float16 half8 __attribute__((ext_vector_type(8)));
typedef __fp16   fp16x2 __attribute__((ext_vector_type(2)));
typedef float floatx4 __attribute__((ext_vector_type(4)));

// ---------------- prep (R27, kept): 256 blocks x 1024 thr, wave-split K --------
__global__ __launch_bounds__(1024) void prep(const float* __restrict__ X,
                                             const float* __restrict__ W1,
                                             float* __restrict__ S,
                                             float* __restrict__ T,
                                             _Float16* __restrict__ Wst) {
  const int g = blockIdx.x;    // 0..255 -> rows 4g..4g+3; Wst conversion d = g
  const int t = threadIdx.x;   // 0..1023

  __shared__ float xr[4][256];            // 4 KB
  __shared__ float part[2][4][4][256];    // 32 KB  [S/T][row][kq][h]

  if (t < 256) {   // weight conversion for d = g (R13 map, unchanged)
    const float wcv = W1[(size_t)(2 * DD + g) * HH + t];
    const float wdv = W1[(size_t)(3 * DD + g) * HH + t];
    const int ks = g >> 4;
    const int dd = g & 15;
    const int q  = dd >> 2;
    const int e  = (dd & 3) * 2;
    const int hgrp = t >> 4;
    const int ccw  = t & 15;
    _Float16* p = Wst + ((size_t)((ks * 16 + hgrp) * 4 + q) * 16 + ccw) * 8 + e;
    p[0] = (_Float16)wcv;
    p[1] = (_Float16)wdv;
  }

  const int row0 = g * 4;
  xr[t >> 8][t & 255] = X[(size_t)row0 * DD + t];
  __syncthreads();

  const int w    = t >> 6;     // wave 0..15
  const int lane = t & 63;
  const int r    = w >> 2;     // row 0..3
  const int kq   = w & 3;      // K-quarter 0..3
  const int h0   = lane * 4;
  const float* __restrict__ xrow = xr[r];
  const int dbase = kq * 64;

  float sa0 = 0.f, sa1 = 0.f, sa2 = 0.f, sa3 = 0.f;
  float sb0 = 0.f, sb1 = 0.f, sb2 = 0.f, sb3 = 0.f;
#pragma unroll 4
  for (int dd = 0; dd < 64; ++dd) {
    const int d = dbase + dd;
    const float4 wa = *(const float4*)&W1[(size_t)d * HH + h0];
    const float4 wb = *(const float4*)&W1[(size_t)(DD + d) * HH + h0];
    const float x = xrow[d];
    sa0 = fmaf(x, wa.x, sa0); sa1 = fmaf(x, wa.y, sa1);
    sa2 = fmaf(x, wa.z, sa2); sa3 = fmaf(x, wa.w, sa3);
    sb0 = fmaf(x, wb.x, sb0); sb1 = fmaf(x, wb.y, sb1);
    sb2 = fmaf(x, wb.z, sb2); sb3 = fmaf(x, wb.w, sb3);
  }
  *(float4*)&part[0][r][kq][h0] = make_float4(sa0, sa1, sa2, sa3);
  *(float4*)&part[1][r][kq][h0] = make_float4(sb0, sb1, sb2, sb3);
  __syncthreads();

  const int rr = t >> 8, hh = t & 255;
  S[(size_t)(row0 + rr) * HH + hh] =
      (part[0][rr][0][hh] + part[0][rr][1][hh]) +
      (part[0][rr][2][hh] + part[0][rr][3][hh]);
  T[(size_t)(row0 + rr) * HH + hh] =
      (part[1][rr][0][hh] + part[1][rr][1][hh]) +
      (part[1][rr][2][hh] + part[1][rr][3][hh]);
}

__device__ __forceinline__ half8 make_afrag(const float4 xi, const float4 xj) {
  fp16x2 p0 = __builtin_amdgcn_cvt_pkrtz(__builtin_fabsf(xi.x - xj.x), xi.x * xj.x);
  fp16x2 p1 = __builtin_amdgcn_cvt_pkrtz(__builtin_fabsf(xi.y - xj.y), xi.y * xj.y);
  fp16x2 p2 = __builtin_amdgcn_cvt_pkrtz(__builtin_fabsf(xi.z - xj.z), xi.z * xj.z);
  fp16x2 p3 = __builtin_amdgcn_cvt_pkrtz(__builtin_fabsf(xi.w - xj.w), xi.w * xj.w);
  uint4 u;
  u.x = __builtin_bit_cast(unsigned int, p0);
  u.y = __builtin_bit_cast(unsigned int, p1);
  u.z = __builtin_bit_cast(unsigned int, p2);
  u.w = __builtin_bit_cast(unsigned int, p3);
  return __builtin_bit_cast(half8, u);
}

#define MFMA16(af, bf, acc) acc = __builtin_amdgcn_mfma_f32_16x16x32_f16(af, bf, acc, 0, 0, 0)

// ---------------- score: 3 blocks/CU = 3 independent phase-streams (R28) -------
// Ledger: per SIMD per generation, matrix needs ~10K cyc, VALU ~17K, measured
// ~45K -> ~18K both-idle. Streams/SIMD has been 2 in EVERY round (the barrier-
// convoyed block phases can't fill each other's gaps with only 2 streams).
// R28: LDS 71.7->38 KB (2-phase Af staging, R23 showed full-K was neutral) and
// launch_bounds (512,6): natural regs ~72-80 < 85 cap (A-prefetch dropped -16,
// epilogue tv-hoist halved -16) -> 3 blocks/CU, 6 waves/SIMD, no squeeze.
// Math bit-identical -> absmax must stay 3.051758e-05.
// Falsifiers: WRITE>10MB spill; occ ~60 but score >=92us -> theory dead, stop.
__global__ __launch_bounds__(512, 6) void score_mfma(
    const float* __restrict__ X,  const float* __restrict__ b1,
    const float* __restrict__ W2, const float* __restrict__ b2,
    const float* __restrict__ S,  const float* __restrict__ T,
    const _Float16* __restrict__ Wst, float* __restrict__ Sc) {

  const int beta = blockIdx.x;      // 0..639, qt-major (R25)
  const int b    = blockIdx.y;
  int i, qt;
  if (beta < 64)       { qt = 0; i = beta; }
  else if (beta < 192) { qt = 1; i = beta - 64; }
  else if (beta < 384) { qt = 2; i = beta - 192; }
  else                 { qt = 3; i = beta - 384; }
  const int bi    = b * NN + i;
  const int jbase = qt * 64;
  const int isUp  = qt > (i >> 6);  // block-uniform

  const int t     = threadIdx.x;    // 0..511
  const int lane  = t & 63;
  const int hg    = t >> 6;         // wave id 0..7 -> h-slice of 32
  const int q     = lane >> 4;
  const int cc    = lane & 15;

  __shared__ __align__(16) float    xi_s[DD];        // 1 KB
  __shared__ __align__(16) _Float16 Af[16384];       // 32 KB (per-half staging)
  __shared__ float pre_s[HH];
  __shared__ float pre2_s[HH];
  __shared__ float w2_s[HH];
  __shared__ float sc_s[8][64];

  if (t < 256) {
    xi_s[t]  = X[(size_t)bi * DD + t];
    pre_s[t] = S[(size_t)bi * HH + t] + b1[t];
  } else {
    const int u = t - 256;
    pre2_s[u] = T[(size_t)bi * HH + u] + b1[u];
    w2_s[u]   = W2[u];
  }

  const float* __restrict__ Tb = T + (size_t)b * NN * HH;
  const float* __restrict__ Sb = S + (size_t)b * NN * HH;

  const int jloc = t & 63;
  const int jg   = jloc >> 4;
  const int ccw  = jloc & 15;
  const float* __restrict__ xjrow = X + (size_t)(b * NN + jbase + jloc) * DD;

  const char* __restrict__ bsrc = (const char*)Wst + hg * 2048 + (size_t)lane * 16;

  floatx4 acc0[4], acc1[4];
#pragma unroll
  for (int u = 0; u < 4; ++u) { acc0[u] = (floatx4)0.f; acc1[u] = (floatx4)0.f; }

  // B prefetch, 2-deep ring across halves (global Wst, barrier-independent)
  half8 Bf0[2], Bf1[2];
#pragma unroll
  for (int u = 0; u < 2; ++u) {
    Bf0[u] = *(const half8*)(bsrc + (size_t)u * 16384);
    Bf1[u] = *(const half8*)(bsrc + (size_t)u * 16384 + 1024);
  }

#pragma unroll 1
  for (int half = 0; half < 2; ++half) {
    __syncthreads();                 // header ready / prior Af reads done

#pragma unroll
    for (int idx = 0; idx < 4; ++idx) {
      const int ksq = hg * 4 + idx;             // 0..31 within half
      const int d0  = (half * 32 + ksq) * 4;
      const int ksl = ksq >> 2;
      const int qw  = ksq & 3;
      const float4 xi4 = *(const float4*)&xi_s[d0];
      const float4 xj4 = *(const float4*)(xjrow + d0);
      *(half8*)&Af[(ksl * 16 + jg * 4 + qw) * 128 + ccw * 8] = make_afrag(xi4, xj4);
    }
    __syncthreads();                 // Af ready; K-loop barrier-free

#pragma unroll
    for (int ksl = 0; ksl < 8; ++ksl) {
      const int s = ksl & 1;                    // static under full unroll
      const half8 Bc0 = Bf0[s], Bc1 = Bf1[s];
      {                                          // prefetch kg+2 (wrap at tail)
        const int kn = (half * 8 + ksl + 2) & 15;
        const char* bk = bsrc + (size_t)kn * 16384;
        Bf0[s] = *(const half8*)(bk);
        Bf1[s] = *(const half8*)(bk + 1024);
      }
      // A read in-step from LDS (no prefetch: -16 regs for the 6-wave cap)
      const _Float16* ap = &Af[ksl * 2048 + lane * 8];
      const half8 A0 = *(const half8*)(ap);
      const half8 A1 = *(const half8*)(ap + 512);
      const half8 A2 = *(const half8*)(ap + 1024);
      const half8 A3 = *(const half8*)(ap + 1536);
      MFMA16(A0, Bc0, acc0[0]); MFMA16(A0, Bc1, acc1[0]);
      MFMA16(A1, Bc0, acc0[1]); MFMA16(A1, Bc1, acc1[1]);
      MFMA16(A2, Bc0, acc0[2]); MFMA16(A2, Bc1, acc1[2]);
      MFMA16(A3, Bc0, acc0[3]); MFMA16(A3, Bc1, acc1[3]);
    }
  }

  // ---- epilogues: two 16-deep tv batches (halved peak live for 6-wave cap) ----
  const int h0   = hg * 32 + cc;
  const int h1   = h0 + 16;
  const int jrow = jbase + q * 4;

#define EPILOGUE(VROW, PRE) {                                                   \
    const float w20 = w2_s[h0], pv0 = PRE[h0];                                  \
    const float w21 = w2_s[h1], pv1 = PRE[h1];                                  \
    float p[16];                                                                \
    {                                                                           \
      float tv[16];                                                             \
      _Pragma("unroll")                                                         \
      for (int u = 0; u < 16; ++u) {                                            \
        const size_t j = (size_t)(jrow + (u >> 2) * 16 + (u & 3)) * HH;         \
        tv[u] = VROW[j + h0];                                                   \
      }                                                                         \
      _Pragma("unroll")                                                         \
      for (int u = 0; u < 16; ++u) {                                            \
        const float hv0 = acc0[u >> 2][u & 3] + pv0 + tv[u];                    \
        const float sv0 = hv0 * __builtin_amdgcn_rcpf(1.f + __expf(-hv0));      \
        p[u] = sv0 * w20;                                                       \
      }                                                                         \
    }                                                                           \
    {                                                                           \
      float tv[16];                                                             \
      _Pragma("unroll")                                                         \
      for (int u = 0; u < 16; ++u) {                                            \
        const size_t j = (size_t)(jrow + (u >> 2) * 16 + (u & 3)) * HH;         \
        tv[u] = VROW[j + h1];                                                   \
      }                                                                         \
      _Pragma("unroll")                                                         \
      for (int u = 0; u < 16; ++u) {                                            \
        const float hv1 = acc1[u >> 2][u & 3] + pv1 + tv[u];                    \
        const float sv1 = hv1 * __builtin_amdgcn_rcpf(1.f + __expf(-hv1));      \
        p[u] = fmaf(sv1, w21, p[u]);                                            \
      }                                                                         \
    }                                                                           \
    _Pragma("unroll")                                                           \
    for (int u = 0; u < 16; ++u) {                                              \
      float v = p[u];                                                           \
      v += __shfl_xor(v, 1); v += __shfl_xor(v, 2);                             \
      v += __shfl_xor(v, 4); v += __shfl_xor(v, 8);                             \
      if (cc == 0) sc_s[hg][(u >> 2) * 16 + q * 4 + (u & 3)] = v;               \
    } }

  // direct: H = C + (S_i+b1) + T_j
  EPILOGUE(Tb, pre_s)
  __syncthreads();

  if (t < 64) {
    float s = sc_s[0][t] + sc_s[1][t] + sc_s[2][t] + sc_s[3][t]
            + sc_s[4][t] + sc_s[5][t] + sc_s[6][t] + sc_s[7][t] + b2[0];
    const int jg2 = jbase + t;
    if (jg2 == i) s = NEGV;
    Sc[(size_t)bi * NN + jg2] = s;
  }

  // mirror (pure-upper blocks): H' = C + S_j + (T_i+b1)
  if (isUp) {
    __syncthreads();                // sc_s reads done before overwrite
    EPILOGUE(Sb, pre2_s)
    __syncthreads();
    if (t < 64) {
      const float s = sc_s[0][t] + sc_s[1][t] + sc_s[2][t] + sc_s[3][t]
                    + sc_s[4][t] + sc_s[5][t] + sc_s[6][t] + sc_s[7][t] + b2[0];
      Sc[(size_t)(b * NN + jbase + t) * NN + i] = s;   // Sc[j, i]
    }
  }
#undef EPILOGUE
}

// ---------------- softmax: 1 wave per row, barrier-free ------------------------
__global__ __launch_bounds__(256) void softmax_kernel(const float* __restrict__ Sc,
                                                      float* __restrict__ out) {
  const int w    = threadIdx.x >> 6;        // wave 0..3
  const int lane = threadIdx.x & 63;
  const int bi   = blockIdx.x * 4 + w;      // row 0..1023
  const float4 v = *(const float4*)&Sc[(size_t)bi * NN + lane * 4];
  float m = fmaxf(fmaxf(v.x, v.y), fmaxf(v.z, v.w));
  m = fmaxf(m, __shfl_xor(m, 1));  m = fmaxf(m, __shfl_xor(m, 2));
  m = fmaxf(m, __shfl_xor(m, 4));  m = fmaxf(m, __shfl_xor(m, 8));
  m = fmaxf(m, __shfl_xor(m, 16)); m = fmaxf(m, __shfl_xor(m, 32));
  const float e0 = __expf(v.x - m), e1 = __expf(v.y - m);
  const float e2 = __expf(v.z - m), e3 = __expf(v.w - m);
  float sum = (e0 + e1) + (e2 + e3);
  sum += __shfl_xor(sum, 1);  sum += __shfl_xor(sum, 2);
  sum += __shfl_xor(sum, 4);  sum += __shfl_xor(sum, 8);
  sum += __shfl_xor(sum, 16); sum += __shfl_xor(sum, 32);
  const float r = 1.f / sum;
  float4 o; o.x = e0 * r; o.y = e1 * r; o.z = e2 * r; o.w = e3 * r;
  *(float4*)&out[(size_t)bi * NN + lane * 4] = o;
}

extern "C" void kernel_launch(void* const* d_in, const int* in_sizes, int n_in,
                              void* d_out, int out_size, void* d_ws, size_t ws_size,
                              hipStream_t stream) {
  const float* X  = (const float*)d_in[0];
  const float* W1 = (const float*)d_in[1];
  const float* b1 = (const float*)d_in[2];
  const float* W2 = (const float*)d_in[3];
  const float* b2 = (const float*)d_in[4];
  float* out = (float*)d_out;

  float*     Sws = (float*)d_ws;                             // 1 MB
  float*     Tws = Sws + (size_t)BB * NN * HH;               // 1 MB
  _Float16*  Wst = (_Float16*)(Tws + (size_t)BB * NN * HH);  // 256 KB
  float*     Scw = (float*)(Wst + (size_t)16 * HH * 32);     // 1 MB

  prep<<<256, 1024, 0, stream>>>(X, W1, Sws, Tws, Wst);
  score_mfma<<<dim3(640, BB), 512, 0, stream>>>(X, b1, W2, b2, Sws, Tws, Wst, Scw);
  softmax_kernel<<<BB * NN / 4, 256, 0, stream>>>(Scw, out);
}

// Round 10
// 167.663 us; speedup vs baseline: 1.6431x; 1.6431x over previous
//
#include <hip/hip_runtime.h>

#define BB 4
#define NN 256
#define DD 256
#define HH 256
#define NEGV -1.0e9f

typedef _Float16 half8 __attribute__((ext_vector_type(8)));
typedef __fp16   fp16x2 __attribute__((ext_vector_type(2)));
typedef float floatx4 __attribute__((ext_vector_type(4)));

// ---------------- prep (R27, kept): 256 blocks x 1024 thr, wave-split K --------
__global__ __launch_bounds__(1024) void prep(const float* __restrict__ X,
                                             const float* __restrict__ W1,
                                             float* __restrict__ S,
                                             float* __restrict__ T,
                                             _Float16* __restrict__ Wst) {
  const int g = blockIdx.x;    // 0..255 -> rows 4g..4g+3; Wst conversion d = g
  const int t = threadIdx.x;   // 0..1023

  __shared__ float xr[4][256];            // 4 KB
  __shared__ float part[2][4][4][256];    // 32 KB  [S/T][row][kq][h]

  if (t < 256) {   // weight conversion for d = g (R13 map, unchanged)
    const float wcv = W1[(size_t)(2 * DD + g) * HH + t];
    const float wdv = W1[(size_t)(3 * DD + g) * HH + t];
    const int ks = g >> 4;
    const int dd = g & 15;
    const int q  = dd >> 2;
    const int e  = (dd & 3) * 2;
    const int hgrp = t >> 4;
    const int ccw  = t & 15;
    _Float16* p = Wst + ((size_t)((ks * 16 + hgrp) * 4 + q) * 16 + ccw) * 8 + e;
    p[0] = (_Float16)wcv;
    p[1] = (_Float16)wdv;
  }

  const int row0 = g * 4;
  xr[t >> 8][t & 255] = X[(size_t)row0 * DD + t];
  __syncthreads();

  const int w    = t >> 6;     // wave 0..15
  const int lane = t & 63;
  const int r    = w >> 2;     // row 0..3
  const int kq   = w & 3;      // K-quarter 0..3
  const int h0   = lane * 4;
  const float* __restrict__ xrow = xr[r];
  const int dbase = kq * 64;

  float sa0 = 0.f, sa1 = 0.f, sa2 = 0.f, sa3 = 0.f;
  float sb0 = 0.f, sb1 = 0.f, sb2 = 0.f, sb3 = 0.f;
#pragma unroll 4
  for (int dd = 0; dd < 64; ++dd) {
    const int d = dbase + dd;
    const float4 wa = *(const float4*)&W1[(size_t)d * HH + h0];
    const float4 wb = *(const float4*)&W1[(size_t)(DD + d) * HH + h0];
    const float x = xrow[d];
    sa0 = fmaf(x, wa.x, sa0); sa1 = fmaf(x, wa.y, sa1);
    sa2 = fmaf(x, wa.z, sa2); sa3 = fmaf(x, wa.w, sa3);
    sb0 = fmaf(x, wb.x, sb0); sb1 = fmaf(x, wb.y, sb1);
    sb2 = fmaf(x, wb.z, sb2); sb3 = fmaf(x, wb.w, sb3);
  }
  *(float4*)&part[0][r][kq][h0] = make_float4(sa0, sa1, sa2, sa3);
  *(float4*)&part[1][r][kq][h0] = make_float4(sb0, sb1, sb2, sb3);
  __syncthreads();

  const int rr = t >> 8, hh = t & 255;
  S[(size_t)(row0 + rr) * HH + hh] =
      (part[0][rr][0][hh] + part[0][rr][1][hh]) +
      (part[0][rr][2][hh] + part[0][rr][3][hh]);
  T[(size_t)(row0 + rr) * HH + hh] =
      (part[1][rr][0][hh] + part[1][rr][1][hh]) +
      (part[1][rr][2][hh] + part[1][rr][3][hh]);
}

__device__ __forceinline__ half8 make_afrag(const float4 xi, const float4 xj) {
  fp16x2 p0 = __builtin_amdgcn_cvt_pkrtz(__builtin_fabsf(xi.x - xj.x), xi.x * xj.x);
  fp16x2 p1 = __builtin_amdgcn_cvt_pkrtz(__builtin_fabsf(xi.y - xj.y), xi.y * xj.y);
  fp16x2 p2 = __builtin_amdgcn_cvt_pkrtz(__builtin_fabsf(xi.z - xj.z), xi.z * xj.z);
  fp16x2 p3 = __builtin_amdgcn_cvt_pkrtz(__builtin_fabsf(xi.w - xj.w), xi.w * xj.w);
  uint4 u;
  u.x = __builtin_bit_cast(unsigned int, p0);
  u.y = __builtin_bit_cast(unsigned int, p1);
  u.z = __builtin_bit_cast(unsigned int, p2);
  u.w = __builtin_bit_cast(unsigned int, p3);
  return __builtin_bit_cast(half8, u);
}

#define MFMA16(af, bf, acc) acc = __builtin_amdgcn_mfma_f32_16x16x32_f16(af, bf, acc, 0, 0, 0)

// ---------------- score: R25/R27 structure + XCD-bijective swizzle (R29) -------
// R28 spilled (cap 85 << natural ~110; WRITE 493MB) -> experiment invalid;
// 2 blocks/CU is the register-feasible occupancy frontier at this tile shape.
// R29 reverts to the proven 96us kernel and adds the last zero-risk lever:
// XCD-aware swizzle. Dispatch round-robins consecutive blockIdx.x over 8 XCDs,
// scattering R25's qt-major locality across XCDs. beta=(bx%8)*80+bx/8 (640=8x80,
// bijective) gives each XCD one contiguous qt-chunk -> its 4MB L2 holds one
// 64-j T/S slice (512KB) + Wst (256KB) + X (1MB). Math byte-identical ->
// absmax must stay 3.051758e-05. Falsifier: score 96us +-2% -> declare floor.
__global__ __launch_bounds__(512, 4) void score_mfma(
    const float* __restrict__ X,  const float* __restrict__ b1,
    const float* __restrict__ W2, const float* __restrict__ b2,
    const float* __restrict__ S,  const float* __restrict__ T,
    const _Float16* __restrict__ Wst, float* __restrict__ Sc) {

  const int bx   = blockIdx.x;      // 0..639
  const int beta = (bx & 7) * 80 + (bx >> 3);   // XCD-bijective, qt-major target
  const int b    = blockIdx.y;
  int i, qt;
  if (beta < 64)       { qt = 0; i = beta; }
  else if (beta < 192) { qt = 1; i = beta - 64; }
  else if (beta < 384) { qt = 2; i = beta - 192; }
  else                 { qt = 3; i = beta - 384; }
  const int bi    = b * NN + i;
  const int jbase = qt * 64;
  const int isUp  = qt > (i >> 6);  // block-uniform

  const int t     = threadIdx.x;    // 0..511
  const int lane  = t & 63;
  const int hg    = t >> 6;         // wave id 0..7 -> h-slice of 32
  const int q     = lane >> 4;
  const int cc    = lane & 15;

  __shared__ __align__(16) float    xi_s[DD];
  __shared__ __align__(16) _Float16 Af[32768];   // 64 KB
  __shared__ float pre_s[HH];
  __shared__ float pre2_s[HH];
  __shared__ float w2_s[HH];
  __shared__ float sc_s[8][64];

  if (t < 256) {
    xi_s[t]  = X[(size_t)bi * DD + t];
    pre_s[t] = S[(size_t)bi * HH + t] + b1[t];
  } else {
    const int u = t - 256;
    pre2_s[u] = T[(size_t)bi * HH + u] + b1[u];
    w2_s[u]   = W2[u];
  }

  const float* __restrict__ Tb = T + (size_t)b * NN * HH;
  const float* __restrict__ Sb = S + (size_t)b * NN * HH;

  const int jloc = t & 63;
  const int jg   = jloc >> 4;
  const int ccw  = jloc & 15;
  const float* __restrict__ xjrow = X + (size_t)(b * NN + jbase + jloc) * DD;

  const char* __restrict__ bsrc = (const char*)Wst + hg * 2048 + (size_t)lane * 16;

  half8 Bf0[4], Bf1[4];
#pragma unroll
  for (int u = 0; u < 4; ++u) {
    Bf0[u] = *(const half8*)(bsrc + (size_t)u * 16384);
    Bf1[u] = *(const half8*)(bsrc + (size_t)u * 16384 + 1024);
  }

  __syncthreads();                  // header (xi_s) ready

  {
    const int sgrp = t >> 6;
#pragma unroll
    for (int idx = 0; idx < 8; ++idx) {
      const int ksqg = sgrp * 8 + idx;          // 0..63 k-quads
      const int d0   = ksqg * 4;
      const int kg   = ksqg >> 2;               // 0..15
      const int qw   = ksqg & 3;
      const float4 xi4 = *(const float4*)&xi_s[d0];
      const float4 xj4 = *(const float4*)(xjrow + d0);
      *(half8*)&Af[kg * 2048 + (jg * 4 + qw) * 128 + ccw * 8] = make_afrag(xi4, xj4);
    }
  }
  __syncthreads();                  // Af ready; K-loop barrier-free, 16 steps

  floatx4 acc0[4], acc1[4];
#pragma unroll
  for (int u = 0; u < 4; ++u) { acc0[u] = (floatx4)0.f; acc1[u] = (floatx4)0.f; }

  const _Float16* ap0 = &Af[lane * 8];
  half8 An0 = *(const half8*)(ap0);
  half8 An1 = *(const half8*)(ap0 + 512);
  half8 An2 = *(const half8*)(ap0 + 1024);
  half8 An3 = *(const half8*)(ap0 + 1536);

#pragma unroll
  for (int kg = 0; kg < 16; ++kg) {
    const int s = kg & 3;
    const half8 Bc0 = Bf0[s], Bc1 = Bf1[s];
    const half8 Ac0 = An0, Ac1 = An1, Ac2 = An2, Ac3 = An3;
    if (kg < 12) {
      const char* bk = bsrc + (size_t)(kg + 4) * 16384;
      Bf0[s] = *(const half8*)(bk);
      Bf1[s] = *(const half8*)(bk + 1024);
    }
    if (kg < 15) {
      const _Float16* ap = &Af[(kg + 1) * 2048 + lane * 8];
      An0 = *(const half8*)(ap);
      An1 = *(const half8*)(ap + 512);
      An2 = *(const half8*)(ap + 1024);
      An3 = *(const half8*)(ap + 1536);
    }
    MFMA16(Ac0, Bc0, acc0[0]); MFMA16(Ac0, Bc1, acc1[0]);
    MFMA16(Ac1, Bc0, acc0[1]); MFMA16(Ac1, Bc1, acc1[1]);
    MFMA16(Ac2, Bc0, acc0[2]); MFMA16(Ac2, Bc1, acc1[2]);
    MFMA16(Ac3, Bc0, acc0[3]); MFMA16(Ac3, Bc1, acc1[3]);
  }

  const int h0   = hg * 32 + cc;
  const int h1   = h0 + 16;
  const int jrow = jbase + q * 4;

#define EPILOGUE(VROW, PRE) {                                                   \
    float tv0[16], tv1[16];                                                     \
    _Pragma("unroll")                                                           \
    for (int u = 0; u < 16; ++u) {                                              \
      const size_t j = (size_t)(jrow + (u >> 2) * 16 + (u & 3)) * HH;           \
      tv0[u] = VROW[j + h0];                                                    \
      tv1[u] = VROW[j + h1];                                                    \
    }                                                                           \
    const float w20 = w2_s[h0], pv0 = PRE[h0];                                  \
    const float w21 = w2_s[h1], pv1 = PRE[h1];                                  \
    float p[16];                                                                \
    _Pragma("unroll")                                                           \
    for (int u = 0; u < 16; ++u) {                                              \
      const float hv0 = acc0[u >> 2][u & 3] + pv0 + tv0[u];                     \
      const float sv0 = hv0 * __builtin_amdgcn_rcpf(1.f + __expf(-hv0));        \
      p[u] = sv0 * w20;                                                         \
      const float hv1 = acc1[u >> 2][u & 3] + pv1 + tv1[u];                     \
      const float sv1 = hv1 * __builtin_amdgcn_rcpf(1.f + __expf(-hv1));        \
      p[u] = fmaf(sv1, w21, p[u]);                                              \
    }                                                                           \
    _Pragma("unroll")                                                           \
    for (int u = 0; u < 16; ++u) {                                              \
      float v = p[u];                                                           \
      v += __shfl_xor(v, 1); v += __shfl_xor(v, 2);                             \
      v += __shfl_xor(v, 4); v += __shfl_xor(v, 8);                             \
      if (cc == 0) sc_s[hg][(u >> 2) * 16 + q * 4 + (u & 3)] = v;               \
    } }

  EPILOGUE(Tb, pre_s)
  __syncthreads();

  if (t < 64) {
    float s = sc_s[0][t] + sc_s[1][t] + sc_s[2][t] + sc_s[3][t]
            + sc_s[4][t] + sc_s[5][t] + sc_s[6][t] + sc_s[7][t] + b2[0];
    const int jg2 = jbase + t;
    if (jg2 == i) s = NEGV;
    Sc[(size_t)bi * NN + jg2] = s;
  }

  if (isUp) {
    __syncthreads();
    EPILOGUE(Sb, pre2_s)
    __syncthreads();
    if (t < 64) {
      const float s = sc_s[0][t] + sc_s[1][t] + sc_s[2][t] + sc_s[3][t]
                    + sc_s[4][t] + sc_s[5][t] + sc_s[6][t] + sc_s[7][t] + b2[0];
      Sc[(size_t)(b * NN + jbase + t) * NN + i] = s;   // Sc[j, i]
    }
  }
#undef EPILOGUE
}

// ---------------- softmax: 1 wave per row, barrier-free ------------------------
__global__ __launch_bounds__(256) void softmax_kernel(const float* __restrict__ Sc,
                                                      float* __restrict__ out) {
  const int w    = threadIdx.x >> 6;        // wave 0..3
  const int lane = threadIdx.x & 63;
  const int bi   = blockIdx.x * 4 + w;      // row 0..1023
  const float4 v = *(const float4*)&Sc[(size_t)bi * NN + lane * 4];
  float m = fmaxf(fmaxf(v.x, v.y), fmaxf(v.z, v.w));
  m = fmaxf(m, __shfl_xor(m, 1));  m = fmaxf(m, __shfl_xor(m, 2));
  m = fmaxf(m, __shfl_xor(m, 4));  m = fmaxf(m, __shfl_xor(m, 8));
  m = fmaxf(m, __shfl_xor(m, 16)); m = fmaxf(m, __shfl_xor(m, 32));
  const float e0 = __expf(v.x - m), e1 = __expf(v.y - m);
  const float e2 = __expf(v.z - m), e3 = __expf(v.w - m);
  float sum = (e0 + e1) + (e2 + e3);
  sum += __shfl_xor(sum, 1);  sum += __shfl_xor(sum, 2);
  sum += __shfl_xor(sum, 4);  sum += __shfl_xor(sum, 8);
  sum += __shfl_xor(sum, 16); sum += __shfl_xor(sum, 32);
  const float r = 1.f / sum;
  float4 o; o.x = e0 * r; o.y = e1 * r; o.z = e2 * r; o.w = e3 * r;
  *(float4*)&out[(size_t)bi * NN + lane * 4] = o;
}

extern "C" void kernel_launch(void* const* d_in, const int* in_sizes, int n_in,
                              void* d_out, int out_size, void* d_ws, size_t ws_size,
                              hipStream_t stream) {
  const float* X  = (const float*)d_in[0];
  const float* W1 = (const float*)d_in[1];
  const float* b1 = (const float*)d_in[2];
  const float* W2 = (const float*)d_in[3];
  const float* b2 = (const float*)d_in[4];
  float* out = (float*)d_out;

  float*     Sws = (float*)d_ws;                             // 1 MB
  float*     Tws = Sws + (size_t)BB * NN * HH;               // 1 MB
  _Float16*  Wst = (_Float16*)(Tws + (size_t)BB * NN * HH);  // 256 KB
  float*     Scw = (float*)(Wst + (size_t)16 * HH * 32);     // 1 MB

  prep<<<256, 1024, 0, stream>>>(X, W1, Sws, Tws, Wst);
  score_mfma<<<dim3(640, BB), 512, 0, stream>>>(X, b1, W2, b2, Sws, Tws, Wst, Scw);
  softmax_kernel<<<BB * NN / 4, 256, 0, stream>>>(Scw, out);
}

// Round 11
// 156.694 us; speedup vs baseline: 1.7581x; 1.0700x over previous
//
#include <hip/hip_runtime.h>

#define BB 4
#define NN 256
#define DD 256
#define HH 256
#define NEGV -1.0e9f

typedef _Float16 half8 __attribute__((ext_vector_type(8)));
typedef __fp16   fp16x2 __attribute__((ext_vector_type(2)));
typedef float floatx4 __attribute__((ext_vector_type(4)));

// ---------------- prep (R27, kept): 256 blocks x 1024 thr, wave-split K --------
__global__ __launch_bounds__(1024) void prep(const float* __restrict__ X,
                                             const float* __restrict__ W1,
                                             float* __restrict__ S,
                                             float* __restrict__ T,
                                             _Float16* __restrict__ Wst) {
  const int g = blockIdx.x;    // 0..255 -> rows 4g..4g+3; Wst conversion d = g
  const int t = threadIdx.x;   // 0..1023

  __shared__ float xr[4][256];            // 4 KB
  __shared__ float part[2][4][4][256];    // 32 KB  [S/T][row][kq][h]

  if (t < 256) {   // weight conversion for d = g (R13 map, unchanged)
    const float wcv = W1[(size_t)(2 * DD + g) * HH + t];
    const float wdv = W1[(size_t)(3 * DD + g) * HH + t];
    const int ks = g >> 4;
    const int dd = g & 15;
    const int q  = dd >> 2;
    const int e  = (dd & 3) * 2;
    const int hgrp = t >> 4;
    const int ccw  = t & 15;
    _Float16* p = Wst + ((size_t)((ks * 16 + hgrp) * 4 + q) * 16 + ccw) * 8 + e;
    p[0] = (_Float16)wcv;
    p[1] = (_Float16)wdv;
  }

  const int row0 = g * 4;
  xr[t >> 8][t & 255] = X[(size_t)row0 * DD + t];
  __syncthreads();

  const int w    = t >> 6;     // wave 0..15
  const int lane = t & 63;
  const int r    = w >> 2;     // row 0..3
  const int kq   = w & 3;      // K-quarter 0..3
  const int h0   = lane * 4;
  const float* __restrict__ xrow = xr[r];
  const int dbase = kq * 64;

  float sa0 = 0.f, sa1 = 0.f, sa2 = 0.f, sa3 = 0.f;
  float sb0 = 0.f, sb1 = 0.f, sb2 = 0.f, sb3 = 0.f;
#pragma unroll 4
  for (int dd = 0; dd < 64; ++dd) {
    const int d = dbase + dd;
    const float4 wa = *(const float4*)&W1[(size_t)d * HH + h0];
    const float4 wb = *(const float4*)&W1[(size_t)(DD + d) * HH + h0];
    const float x = xrow[d];
    sa0 = fmaf(x, wa.x, sa0); sa1 = fmaf(x, wa.y, sa1);
    sa2 = fmaf(x, wa.z, sa2); sa3 = fmaf(x, wa.w, sa3);
    sb0 = fmaf(x, wb.x, sb0); sb1 = fmaf(x, wb.y, sb1);
    sb2 = fmaf(x, wb.z, sb2); sb3 = fmaf(x, wb.w, sb3);
  }
  *(float4*)&part[0][r][kq][h0] = make_float4(sa0, sa1, sa2, sa3);
  *(float4*)&part[1][r][kq][h0] = make_float4(sb0, sb1, sb2, sb3);
  __syncthreads();

  const int rr = t >> 8, hh = t & 255;
  S[(size_t)(row0 + rr) * HH + hh] =
      (part[0][rr][0][hh] + part[0][rr][1][hh]) +
      (part[0][rr][2][hh] + part[0][rr][3][hh]);
  T[(size_t)(row0 + rr) * HH + hh] =
      (part[1][rr][0][hh] + part[1][rr][1][hh]) +
      (part[1][rr][2][hh] + part[1][rr][3][hh]);
}

__device__ __forceinline__ half8 make_afrag(const float4 xi, const float4 xj) {
  fp16x2 p0 = __builtin_amdgcn_cvt_pkrtz(__builtin_fabsf(xi.x - xj.x), xi.x * xj.x);
  fp16x2 p1 = __builtin_amdgcn_cvt_pkrtz(__builtin_fabsf(xi.y - xj.y), xi.y * xj.y);
  fp16x2 p2 = __builtin_amdgcn_cvt_pkrtz(__builtin_fabsf(xi.z - xj.z), xi.z * xj.z);
  fp16x2 p3 = __builtin_amdgcn_cvt_pkrtz(__builtin_fabsf(xi.w - xj.w), xi.w * xj.w);
  uint4 u;
  u.x = __builtin_bit_cast(unsigned int, p0);
  u.y = __builtin_bit_cast(unsigned int, p1);
  u.z = __builtin_bit_cast(unsigned int, p2);
  u.w = __builtin_bit_cast(unsigned int, p3);
  return __builtin_bit_cast(half8, u);
}

#define MFMA16(af, bf, acc) acc = __builtin_amdgcn_mfma_f32_16x16x32_f16(af, bf, acc, 0, 0, 0)

// DPP cross-lane add: lane^1 / lane^2 via quad_perm on the VALU pipe.
// Bit-identical to __shfl_xor(v,1/2) (same source lane, same add order) but
// issues ZERO DS-pipe ops. quad_perm(1,0,3,2)=0xB1, quad_perm(2,3,0,1)=0x4E.
__device__ __forceinline__ float dpp_add_xor1(float v) {
  const int s = __builtin_amdgcn_update_dpp(0, __builtin_bit_cast(int, v),
                                            0xB1, 0xF, 0xF, true);
  return v + __builtin_bit_cast(float, s);
}
__device__ __forceinline__ float dpp_add_xor2(float v) {
  const int s = __builtin_amdgcn_update_dpp(0, __builtin_bit_cast(int, v),
                                            0x4E, 0xF, 0xF, true);
  return v + __builtin_bit_cast(float, s);
}

// ---------------- score: R27 structure + DPP reduction (R30) -------------------
// R29: -40% HBM traffic yet +4% time -> NOT memory-bound anywhere; swizzle
// reverted. Hand-count of the uncountered DS pipe (no LDS-busy PMC): K-loop
// A-reads ~25us + shfl-reduction (ds_swizzle) ~20us + staging ~3us = ~48us
// busy on a 96us kernel -> DS is the max pipe, first model matching the
// plateau's magnitude. R30 test: xor1/xor2 reduction steps -> DPP quad_perm
// (VALU pipe), bit-identical lanes/order; reduction DS ops halved.
// absmax must stay exactly 3.051758e-05.
// Falsifier: score 96+-2us -> DS-reduction not critical; 32x32 rewrite or floor.
__global__ __launch_bounds__(512, 4) void score_mfma(
    const float* __restrict__ X,  const float* __restrict__ b1,
    const float* __restrict__ W2, const float* __restrict__ b2,
    const float* __restrict__ S,  const float* __restrict__ T,
    const _Float16* __restrict__ Wst, float* __restrict__ Sc) {

  const int beta = blockIdx.x;      // 0..639, qt-major (R25 decode, no swizzle)
  const int b    = blockIdx.y;
  int i, qt;
  if (beta < 64)       { qt = 0; i = beta; }
  else if (beta < 192) { qt = 1; i = beta - 64; }
  else if (beta < 384) { qt = 2; i = beta - 192; }
  else                 { qt = 3; i = beta - 384; }
  const int bi    = b * NN + i;
  const int jbase = qt * 64;
  const int isUp  = qt > (i >> 6);  // block-uniform

  const int t     = threadIdx.x;    // 0..511
  const int lane  = t & 63;
  const int hg    = t >> 6;         // wave id 0..7 -> h-slice of 32
  const int q     = lane >> 4;
  const int cc    = lane & 15;

  __shared__ __align__(16) float    xi_s[DD];
  __shared__ __align__(16) _Float16 Af[32768];   // 64 KB
  __shared__ float pre_s[HH];
  __shared__ float pre2_s[HH];
  __shared__ float w2_s[HH];
  __shared__ float sc_s[8][64];

  if (t < 256) {
    xi_s[t]  = X[(size_t)bi * DD + t];
    pre_s[t] = S[(size_t)bi * HH + t] + b1[t];
  } else {
    const int u = t - 256;
    pre2_s[u] = T[(size_t)bi * HH + u] + b1[u];
    w2_s[u]   = W2[u];
  }

  const float* __restrict__ Tb = T + (size_t)b * NN * HH;
  const float* __restrict__ Sb = S + (size_t)b * NN * HH;

  const int jloc = t & 63;
  const int jg   = jloc >> 4;
  const int ccw  = jloc & 15;
  const float* __restrict__ xjrow = X + (size_t)(b * NN + jbase + jloc) * DD;

  const char* __restrict__ bsrc = (const char*)Wst + hg * 2048 + (size_t)lane * 16;

  half8 Bf0[4], Bf1[4];
#pragma unroll
  for (int u = 0; u < 4; ++u) {
    Bf0[u] = *(const half8*)(bsrc + (size_t)u * 16384);
    Bf1[u] = *(const half8*)(bsrc + (size_t)u * 16384 + 1024);
  }

  __syncthreads();                  // header (xi_s) ready

  {
    const int sgrp = t >> 6;
#pragma unroll
    for (int idx = 0; idx < 8; ++idx) {
      const int ksqg = sgrp * 8 + idx;          // 0..63 k-quads
      const int d0   = ksqg * 4;
      const int kg   = ksqg >> 2;               // 0..15
      const int qw   = ksqg & 3;
      const float4 xi4 = *(const float4*)&xi_s[d0];
      const float4 xj4 = *(const float4*)(xjrow + d0);
      *(half8*)&Af[kg * 2048 + (jg * 4 + qw) * 128 + ccw * 8] = make_afrag(xi4, xj4);
    }
  }
  __syncthreads();                  // Af ready; K-loop barrier-free, 16 steps

  floatx4 acc0[4], acc1[4];
#pragma unroll
  for (int u = 0; u < 4; ++u) { acc0[u] = (floatx4)0.f; acc1[u] = (floatx4)0.f; }

  const _Float16* ap0 = &Af[lane * 8];
  half8 An0 = *(const half8*)(ap0);
  half8 An1 = *(const half8*)(ap0 + 512);
  half8 An2 = *(const half8*)(ap0 + 1024);
  half8 An3 = *(const half8*)(ap0 + 1536);

#pragma unroll
  for (int kg = 0; kg < 16; ++kg) {
    const int s = kg & 3;
    const half8 Bc0 = Bf0[s], Bc1 = Bf1[s];
    const half8 Ac0 = An0, Ac1 = An1, Ac2 = An2, Ac3 = An3;
    if (kg < 12) {
      const char* bk = bsrc + (size_t)(kg + 4) * 16384;
      Bf0[s] = *(const half8*)(bk);
      Bf1[s] = *(const half8*)(bk + 1024);
    }
    if (kg < 15) {
      const _Float16* ap = &Af[(kg + 1) * 2048 + lane * 8];
      An0 = *(const half8*)(ap);
      An1 = *(const half8*)(ap + 512);
      An2 = *(const half8*)(ap + 1024);
      An3 = *(const half8*)(ap + 1536);
    }
    MFMA16(Ac0, Bc0, acc0[0]); MFMA16(Ac0, Bc1, acc1[0]);
    MFMA16(Ac1, Bc0, acc0[1]); MFMA16(Ac1, Bc1, acc1[1]);
    MFMA16(Ac2, Bc0, acc0[2]); MFMA16(Ac2, Bc1, acc1[2]);
    MFMA16(Ac3, Bc0, acc0[3]); MFMA16(Ac3, Bc1, acc1[3]);
  }

  const int h0   = hg * 32 + cc;
  const int h1   = h0 + 16;
  const int jrow = jbase + q * 4;

#define EPILOGUE(VROW, PRE) {                                                   \
    float tv0[16], tv1[16];                                                     \
    _Pragma("unroll")                                                           \
    for (int u = 0; u < 16; ++u) {                                              \
      const size_t j = (size_t)(jrow + (u >> 2) * 16 + (u & 3)) * HH;           \
      tv0[u] = VROW[j + h0];                                                    \
      tv1[u] = VROW[j + h1];                                                    \
    }                                                                           \
    const float w20 = w2_s[h0], pv0 = PRE[h0];                                  \
    const float w21 = w2_s[h1], pv1 = PRE[h1];                                  \
    float p[16];                                                                \
    _Pragma("unroll")                                                           \
    for (int u = 0; u < 16; ++u) {                                              \
      const float hv0 = acc0[u >> 2][u & 3] + pv0 + tv0[u];                     \
      const float sv0 = hv0 * __builtin_amdgcn_rcpf(1.f + __expf(-hv0));        \
      p[u] = sv0 * w20;                                                         \
      const float hv1 = acc1[u >> 2][u & 3] + pv1 + tv1[u];                     \
      const float sv1 = hv1 * __builtin_amdgcn_rcpf(1.f + __expf(-hv1));        \
      p[u] = fmaf(sv1, w21, p[u]);                                              \
    }                                                                           \
    _Pragma("unroll")                                                           \
    for (int u = 0; u < 16; ++u) {                                              \
      float v = p[u];                                                           \
      v = dpp_add_xor1(v);                                                      \
      v = dpp_add_xor2(v);                                                      \
      v += __shfl_xor(v, 4); v += __shfl_xor(v, 8);                             \
      if (cc == 0) sc_s[hg][(u >> 2) * 16 + q * 4 + (u & 3)] = v;               \
    } }

  EPILOGUE(Tb, pre_s)
  __syncthreads();

  if (t < 64) {
    float s = sc_s[0][t] + sc_s[1][t] + sc_s[2][t] + sc_s[3][t]
            + sc_s[4][t] + sc_s[5][t] + sc_s[6][t] + sc_s[7][t] + b2[0];
    const int jg2 = jbase + t;
    if (jg2 == i) s = NEGV;
    Sc[(size_t)bi * NN + jg2] = s;
  }

  if (isUp) {
    __syncthreads();
    EPILOGUE(Sb, pre2_s)
    __syncthreads();
    if (t < 64) {
      const float s = sc_s[0][t] + sc_s[1][t] + sc_s[2][t] + sc_s[3][t]
                    + sc_s[4][t] + sc_s[5][t] + sc_s[6][t] + sc_s[7][t] + b2[0];
      Sc[(size_t)(b * NN + jbase + t) * NN + i] = s;   // Sc[j, i]
    }
  }
#undef EPILOGUE
}

// ---------------- softmax: 1 wave per row, barrier-free ------------------------
__global__ __launch_bounds__(256) void softmax_kernel(const float* __restrict__ Sc,
                                                      float* __restrict__ out) {
  const int w    = threadIdx.x >> 6;        // wave 0..3
  const int lane = threadIdx.x & 63;
  const int bi   = blockIdx.x * 4 + w;      // row 0..1023
  const float4 v = *(const float4*)&Sc[(size_t)bi * NN + lane * 4];
  float m = fmaxf(fmaxf(v.x, v.y), fmaxf(v.z, v.w));
  m = fmaxf(m, __shfl_xor(m, 1));  m = fmaxf(m, __shfl_xor(m, 2));
  m = fmaxf(m, __shfl_xor(m, 4));  m = fmaxf(m, __shfl_xor(m, 8));
  m = fmaxf(m, __shfl_xor(m, 16)); m = fmaxf(m, __shfl_xor(m, 32));
  const float e0 = __expf(v.x - m), e1 = __expf(v.y - m);
  const float e2 = __expf(v.z - m), e3 = __expf(v.w - m);
  float sum = (e0 + e1) + (e2 + e3);
  sum += __shfl_xor(sum, 1);  sum += __shfl_xor(sum, 2);
  sum += __shfl_xor(sum, 4);  sum += __shfl_xor(sum, 8);
  sum += __shfl_xor(sum, 16); sum += __shfl_xor(sum, 32);
  const float r = 1.f / sum;
  float4 o; o.x = e0 * r; o.y = e1 * r; o.z = e2 * r; o.w = e3 * r;
  *(float4*)&out[(size_t)bi * NN + lane * 4] = o;
}

extern "C" void kernel_launch(void* const* d_in, const int* in_sizes, int n_in,
                              void* d_out, int out_size, void* d_ws, size_t ws_size,
                              hipStream_t stream) {
  const float* X  = (const float*)d_in[0];
  const float* W1 = (const float*)d_in[1];
  const float* b1 = (const float*)d_in[2];
  const float* W2 = (const float*)d_in[3];
  const float* b2 = (const float*)d_in[4];
  float* out = (float*)d_out;

  float*     Sws = (float*)d_ws;                             // 1 MB
  float*     Tws = Sws + (size_t)BB * NN * HH;               // 1 MB
  _Float16*  Wst = (_Float16*)(Tws + (size_t)BB * NN * HH);  // 256 KB
  float*     Scw = (float*)(Wst + (size_t)16 * HH * 32);     // 1 MB

  prep<<<256, 1024, 0, stream>>>(X, W1, Sws, Tws, Wst);
  score_mfma<<<dim3(640, BB), 512, 0, stream>>>(X, b1, W2, b2, Sws, Tws, Wst, Scw);
  softmax_kernel<<<BB * NN / 4, 256, 0, stream>>>(Scw, out);
}

// Round 13
// 155.753 us; speedup vs baseline: 1.7688x; 1.0060x over previous
//
#include <hip/hip_runtime.h>

#define BB 4
#define NN 256
#define DD 256
#define HH 256
#define NEGV -1.0e9f

typedef _Float16 half8 __attribute__((ext_vector_type(8)));
typedef __fp16   fp16x2 __attribute__((ext_vector_type(2)));
typedef float floatx4 __attribute__((ext_vector_type(4)));

// ---------------- prep (R27, kept): 256 blocks x 1024 thr, wave-split K --------
__global__ __launch_bounds__(1024) void prep(const float* __restrict__ X,
                                             const float* __restrict__ W1,
                                             float* __restrict__ S,
                                             float* __restrict__ T,
                                             _Float16* __restrict__ Wst) {
  const int g = blockIdx.x;    // 0..255 -> rows 4g..4g+3; Wst conversion d = g
  const int t = threadIdx.x;   // 0..1023

  __shared__ float xr[4][256];            // 4 KB
  __shared__ float part[2][4][4][256];    // 32 KB  [S/T][row][kq][h]

  if (t < 256) {   // weight conversion for d = g (R13 map, unchanged)
    const float wcv = W1[(size_t)(2 * DD + g) * HH + t];
    const float wdv = W1[(size_t)(3 * DD + g) * HH + t];
    const int ks = g >> 4;
    const int dd = g & 15;
    const int q  = dd >> 2;
    const int e  = (dd & 3) * 2;
    const int hgrp = t >> 4;
    const int ccw  = t & 15;
    _Float16* p = Wst + ((size_t)((ks * 16 + hgrp) * 4 + q) * 16 + ccw) * 8 + e;
    p[0] = (_Float16)wcv;
    p[1] = (_Float16)wdv;
  }

  const int row0 = g * 4;
  xr[t >> 8][t & 255] = X[(size_t)row0 * DD + t];
  __syncthreads();

  const int w    = t >> 6;     // wave 0..15
  const int lane = t & 63;
  const int r    = w >> 2;     // row 0..3
  const int kq   = w & 3;      // K-quarter 0..3
  const int h0   = lane * 4;
  const float* __restrict__ xrow = xr[r];
  const int dbase = kq * 64;

  float sa0 = 0.f, sa1 = 0.f, sa2 = 0.f, sa3 = 0.f;
  float sb0 = 0.f, sb1 = 0.f, sb2 = 0.f, sb3 = 0.f;
#pragma unroll 4
  for (int dd = 0; dd < 64; ++dd) {
    const int d = dbase + dd;
    const float4 wa = *(const float4*)&W1[(size_t)d * HH + h0];
    const float4 wb = *(const float4*)&W1[(size_t)(DD + d) * HH + h0];
    const float x = xrow[d];
    sa0 = fmaf(x, wa.x, sa0); sa1 = fmaf(x, wa.y, sa1);
    sa2 = fmaf(x, wa.z, sa2); sa3 = fmaf(x, wa.w, sa3);
    sb0 = fmaf(x, wb.x, sb0); sb1 = fmaf(x, wb.y, sb1);
    sb2 = fmaf(x, wb.z, sb2); sb3 = fmaf(x, wb.w, sb3);
  }
  *(float4*)&part[0][r][kq][h0] = make_float4(sa0, sa1, sa2, sa3);
  *(float4*)&part[1][r][kq][h0] = make_float4(sb0, sb1, sb2, sb3);
  __syncthreads();

  const int rr = t >> 8, hh = t & 255;
  S[(size_t)(row0 + rr) * HH + hh] =
      (part[0][rr][0][hh] + part[0][rr][1][hh]) +
      (part[0][rr][2][hh] + part[0][rr][3][hh]);
  T[(size_t)(row0 + rr) * HH + hh] =
      (part[1][rr][0][hh] + part[1][rr][1][hh]) +
      (part[1][rr][2][hh] + part[1][rr][3][hh]);
}

__device__ __forceinline__ half8 make_afrag(const float4 xi, const float4 xj) {
  fp16x2 p0 = __builtin_amdgcn_cvt_pkrtz(__builtin_fabsf(xi.x - xj.x), xi.x * xj.x);
  fp16x2 p1 = __builtin_amdgcn_cvt_pkrtz(__builtin_fabsf(xi.y - xj.y), xi.y * xj.y);
  fp16x2 p2 = __builtin_amdgcn_cvt_pkrtz(__builtin_fabsf(xi.z - xj.z), xi.z * xj.z);
  fp16x2 p3 = __builtin_amdgcn_cvt_pkrtz(__builtin_fabsf(xi.w - xj.w), xi.w * xj.w);
  uint4 u;
  u.x = __builtin_bit_cast(unsigned int, p0);
  u.y = __builtin_bit_cast(unsigned int, p1);
  u.z = __builtin_bit_cast(unsigned int, p2);
  u.w = __builtin_bit_cast(unsigned int, p3);
  return __builtin_bit_cast(half8, u);
}

#define MFMA16(af, bf, acc) acc = __builtin_amdgcn_mfma_f32_16x16x32_f16(af, bf, acc, 0, 0, 0)

// Cross-lane adds on the VALU pipe via DPP — ZERO DS-pipe ops.
// CTRL must be an ICE for the builtin -> template parameter (R31 compile fix).
// quad_perm(1,0,3,2)=0xB1 == xor1; quad_perm(2,3,0,1)=0x4E == xor2.
// row_half_mirror(0x141): lane reads (7-(l&7)) — after xor1+xor2 all quad
// lanes hold identical bits, so this pairs the SAME VALUES as xor4;
// row_mirror(0x140): lane reads (15-(l&15)) — same values as xor8. FP add is
// bitwise commutative -> results bit-identical to the shfl_xor butterfly.
// The 16-lane reduce group (lane&~15) == a DPP row: row ops never cross groups.
template <int CTRL>
__device__ __forceinline__ float dpp_add(float v) {
  const int s = __builtin_amdgcn_update_dpp(0, __builtin_bit_cast(int, v),
                                            CTRL, 0xF, 0xF, true);
  return v + __builtin_bit_cast(float, s);
}

// ---------------- score: R30 structure + full-VALU reduction (R32=R31 fix) -----
// R30 confirmed the DS-pipe model: halving reduction DS ops bought -7.5us
// (96->88.5). This removes the REST of the reduction's DS ops (xor4->row_half_
// mirror, xor8->row_mirror): reduction = 4 DPP adds, all VALU. Remaining DS =
// A-reads ~25us + staging ~3us; VALU (~40us) becomes the top pipe.
// absmax must stay exactly 3.051758e-05 (bit-identical per commutativity).
// Falsifier: score 88.5+-1.5 -> only A-read DS left -> 32x32 MFMA or stop.
__global__ __launch_bounds__(512, 4) void score_mfma(
    const float* __restrict__ X,  const float* __restrict__ b1,
    const float* __restrict__ W2, const float* __restrict__ b2,
    const float* __restrict__ S,  const float* __restrict__ T,
    const _Float16* __restrict__ Wst, float* __restrict__ Sc) {

  const int beta = blockIdx.x;      // 0..639, qt-major (R25 decode, no swizzle)
  const int b    = blockIdx.y;
  int i, qt;
  if (beta < 64)       { qt = 0; i = beta; }
  else if (beta < 192) { qt = 1; i = beta - 64; }
  else if (beta < 384) { qt = 2; i = beta - 192; }
  else                 { qt = 3; i = beta - 384; }
  const int bi    = b * NN + i;
  const int jbase = qt * 64;
  const int isUp  = qt > (i >> 6);  // block-uniform

  const int t     = threadIdx.x;    // 0..511
  const int lane  = t & 63;
  const int hg    = t >> 6;         // wave id 0..7 -> h-slice of 32
  const int q     = lane >> 4;
  const int cc    = lane & 15;

  __shared__ __align__(16) float    xi_s[DD];
  __shared__ __align__(16) _Float16 Af[32768];   // 64 KB
  __shared__ float pre_s[HH];
  __shared__ float pre2_s[HH];
  __shared__ float w2_s[HH];
  __shared__ float sc_s[8][64];

  if (t < 256) {
    xi_s[t]  = X[(size_t)bi * DD + t];
    pre_s[t] = S[(size_t)bi * HH + t] + b1[t];
  } else {
    const int u = t - 256;
    pre2_s[u] = T[(size_t)bi * HH + u] + b1[u];
    w2_s[u]   = W2[u];
  }

  const float* __restrict__ Tb = T + (size_t)b * NN * HH;
  const float* __restrict__ Sb = S + (size_t)b * NN * HH;

  const int jloc = t & 63;
  const int jg   = jloc >> 4;
  const int ccw  = jloc & 15;
  const float* __restrict__ xjrow = X + (size_t)(b * NN + jbase + jloc) * DD;

  const char* __restrict__ bsrc = (const char*)Wst + hg * 2048 + (size_t)lane * 16;

  half8 Bf0[4], Bf1[4];
#pragma unroll
  for (int u = 0; u < 4; ++u) {
    Bf0[u] = *(const half8*)(bsrc + (size_t)u * 16384);
    Bf1[u] = *(const half8*)(bsrc + (size_t)u * 16384 + 1024);
  }

  __syncthreads();                  // header (xi_s) ready

  {
    const int sgrp = t >> 6;
#pragma unroll
    for (int idx = 0; idx < 8; ++idx) {
      const int ksqg = sgrp * 8 + idx;          // 0..63 k-quads
      const int d0   = ksqg * 4;
      const int kg   = ksqg >> 2;               // 0..15
      const int qw   = ksqg & 3;
      const float4 xi4 = *(const float4*)&xi_s[d0];
      const float4 xj4 = *(const float4*)(xjrow + d0);
      *(half8*)&Af[kg * 2048 + (jg * 4 + qw) * 128 + ccw * 8] = make_afrag(xi4, xj4);
    }
  }
  __syncthreads();                  // Af ready; K-loop barrier-free, 16 steps

  floatx4 acc0[4], acc1[4];
#pragma unroll
  for (int u = 0; u < 4; ++u) { acc0[u] = (floatx4)0.f; acc1[u] = (floatx4)0.f; }

  const _Float16* ap0 = &Af[lane * 8];
  half8 An0 = *(const half8*)(ap0);
  half8 An1 = *(const half8*)(ap0 + 512);
  half8 An2 = *(const half8*)(ap0 + 1024);
  half8 An3 = *(const half8*)(ap0 + 1536);

#pragma unroll
  for (int kg = 0; kg < 16; ++kg) {
    const int s = kg & 3;
    const half8 Bc0 = Bf0[s], Bc1 = Bf1[s];
    const half8 Ac0 = An0, Ac1 = An1, Ac2 = An2, Ac3 = An3;
    if (kg < 12) {
      const char* bk = bsrc + (size_t)(kg + 4) * 16384;
      Bf0[s] = *(const half8*)(bk);
      Bf1[s] = *(const half8*)(bk + 1024);
    }
    if (kg < 15) {
      const _Float16* ap = &Af[(kg + 1) * 2048 + lane * 8];
      An0 = *(const half8*)(ap);
      An1 = *(const half8*)(ap + 512);
      An2 = *(const half8*)(ap + 1024);
      An3 = *(const half8*)(ap + 1536);
    }
    MFMA16(Ac0, Bc0, acc0[0]); MFMA16(Ac0, Bc1, acc1[0]);
    MFMA16(Ac1, Bc0, acc0[1]); MFMA16(Ac1, Bc1, acc1[1]);
    MFMA16(Ac2, Bc0, acc0[2]); MFMA16(Ac2, Bc1, acc1[2]);
    MFMA16(Ac3, Bc0, acc0[3]); MFMA16(Ac3, Bc1, acc1[3]);
  }

  const int h0   = hg * 32 + cc;
  const int h1   = h0 + 16;
  const int jrow = jbase + q * 4;

#define EPILOGUE(VROW, PRE) {                                                   \
    float tv0[16], tv1[16];                                                     \
    _Pragma("unroll")                                                           \
    for (int u = 0; u < 16; ++u) {                                              \
      const size_t j = (size_t)(jrow + (u >> 2) * 16 + (u & 3)) * HH;           \
      tv0[u] = VROW[j + h0];                                                    \
      tv1[u] = VROW[j + h1];                                                    \
    }                                                                           \
    const float w20 = w2_s[h0], pv0 = PRE[h0];                                  \
    const float w21 = w2_s[h1], pv1 = PRE[h1];                                  \
    float p[16];                                                                \
    _Pragma("unroll")                                                           \
    for (int u = 0; u < 16; ++u) {                                              \
      const float hv0 = acc0[u >> 2][u & 3] + pv0 + tv0[u];                     \
      const float sv0 = hv0 * __builtin_amdgcn_rcpf(1.f + __expf(-hv0));        \
      p[u] = sv0 * w20;                                                         \
      const float hv1 = acc1[u >> 2][u & 3] + pv1 + tv1[u];                     \
      const float sv1 = hv1 * __builtin_amdgcn_rcpf(1.f + __expf(-hv1));        \
      p[u] = fmaf(sv1, w21, p[u]);                                              \
    }                                                                           \
    _Pragma("unroll")                                                           \
    for (int u = 0; u < 16; ++u) {                                              \
      float v = p[u];                                                           \
      v = dpp_add<0xB1>(v);    /* xor1: quad_perm(1,0,3,2) */                   \
      v = dpp_add<0x4E>(v);    /* xor2: quad_perm(2,3,0,1) */                   \
      v = dpp_add<0x141>(v);   /* xor4-equivalent: row_half_mirror */           \
      v = dpp_add<0x140>(v);   /* xor8-equivalent: row_mirror */                \
      if (cc == 0) sc_s[hg][(u >> 2) * 16 + q * 4 + (u & 3)] = v;               \
    } }

  EPILOGUE(Tb, pre_s)
  __syncthreads();

  if (t < 64) {
    float s = sc_s[0][t] + sc_s[1][t] + sc_s[2][t] + sc_s[3][t]
            + sc_s[4][t] + sc_s[5][t] + sc_s[6][t] + sc_s[7][t] + b2[0];
    const int jg2 = jbase + t;
    if (jg2 == i) s = NEGV;
    Sc[(size_t)bi * NN + jg2] = s;
  }

  if (isUp) {
    __syncthreads();
    EPILOGUE(Sb, pre2_s)
    __syncthreads();
    if (t < 64) {
      const float s = sc_s[0][t] + sc_s[1][t] + sc_s[2][t] + sc_s[3][t]
                    + sc_s[4][t] + sc_s[5][t] + sc_s[6][t] + sc_s[7][t] + b2[0];
      Sc[(size_t)(b * NN + jbase + t) * NN + i] = s;   // Sc[j, i]
    }
  }
#undef EPILOGUE
}

// ---------------- softmax: 1 wave per row, barrier-free ------------------------
__global__ __launch_bounds__(256) void softmax_kernel(const float* __restrict__ Sc,
                                                      float* __restrict__ out) {
  const int w    = threadIdx.x >> 6;        // wave 0..3
  const int lane = threadIdx.x & 63;
  const int bi   = blockIdx.x * 4 + w;      // row 0..1023
  const float4 v = *(const float4*)&Sc[(size_t)bi * NN + lane * 4];
  float m = fmaxf(fmaxf(v.x, v.y), fmaxf(v.z, v.w));
  m = fmaxf(m, __shfl_xor(m, 1));  m = fmaxf(m, __shfl_xor(m, 2));
  m = fmaxf(m, __shfl_xor(m, 4));  m = fmaxf(m, __shfl_xor(m, 8));
  m = fmaxf(m, __shfl_xor(m, 16)); m = fmaxf(m, __shfl_xor(m, 32));
  const float e0 = __expf(v.x - m), e1 = __expf(v.y - m);
  const float e2 = __expf(v.z - m), e3 = __expf(v.w - m);
  float sum = (e0 + e1) + (e2 + e3);
  sum += __shfl_xor(sum, 1);  sum += __shfl_xor(sum, 2);
  sum += __shfl_xor(sum, 4);  sum += __shfl_xor(sum, 8);
  sum += __shfl_xor(sum, 16); sum += __shfl_xor(sum, 32);
  const float r = 1.f / sum;
  float4 o; o.x = e0 * r; o.y = e1 * r; o.z = e2 * r; o.w = e3 * r;
  *(float4*)&out[(size_t)bi * NN + lane * 4] = o;
}

extern "C" void kernel_launch(void* const* d_in, const int* in_sizes, int n_in,
                              void* d_out, int out_size, void* d_ws, size_t ws_size,
                              hipStream_t stream) {
  const float* X  = (const float*)d_in[0];
  const float* W1 = (const float*)d_in[1];
  const float* b1 = (const float*)d_in[2];
  const float* W2 = (const float*)d_in[3];
  const float* b2 = (const float*)d_in[4];
  float* out = (float*)d_out;

  float*     Sws = (float*)d_ws;                             // 1 MB
  float*     Tws = Sws + (size_t)BB * NN * HH;               // 1 MB
  _Float16*  Wst = (_Float16*)(Tws + (size_t)BB * NN * HH);  // 256 KB
  float*     Scw = (float*)(Wst + (size_t)16 * HH * 32);     // 1 MB

  prep<<<256, 1024, 0, stream>>>(X, W1, Sws, Tws, Wst);
  score_mfma<<<dim3(640, BB), 512, 0, stream>>>(X, b1, W2, b2, Sws, Tws, Wst, Scw);
  softmax_kernel<<<BB * NN / 4, 256, 0, stream>>>(Scw, out);
}